// Round 17
// baseline (197.809 us; speedup 1.0000x reference)
//
#include <hip/hip_runtime.h>
#include <math.h>

#define NN 100000
#define NE 1600000
#define INF 128
#define HID 256
#define SCAN_BLK 256
#define NSCAN ((NN + SCAN_BLK - 1) / SCAN_BLK)   // 391
#define FGRP 8                    // node-space partitions (fill + hist)
#define FRNG (NN / FGRP)          // 12500 nodes per range
#define NC 32                     // edge-stream chunks
#define CHUNK (NE / NC)           // 50000 edges per chunk
#define HISTB 512                 // hist blocks: 2 types x 8 ranges x 32 chunks
#define MIDF (FGRP * NC)          // 256 fill blocks
#define MIDX 256                  // xconv blocks

typedef short bf16x8 __attribute__((ext_vector_type(8)));
typedef float f32x4 __attribute__((ext_vector_type(4)));

__device__ __forceinline__ unsigned int f2bf(float f) {
    unsigned int u = __float_as_uint(f);
    u = u + 0x7FFFu + ((u >> 16) & 1u);   // RNE
    return u >> 16;
}

// ---- degree histograms (512 blocks, 2/CU) ∥ wfrag (512..516) ----
// block (type=bid&1, gp=(bid>>1)&7, c=bid>>4): int LDS counters over
// 12500 nodes (50 KB -> 2 blocks/CU, 32 waves/CU), chunk c of src or dst.
// Flush packs counter pairs into the ushort hop/hip layout (downstream
// kernels unchanged). Zero global atomics.
__launch_bounds__(1024)
__global__ void k_hist(const int* __restrict__ src, const int* __restrict__ dst,
                       unsigned int* __restrict__ hop, unsigned int* __restrict__ hip,
                       const float* __restrict__ W1, const float* __restrict__ b1,
                       const float* __restrict__ W2, unsigned short* __restrict__ fragW,
                       float2* __restrict__ bw) {
    __shared__ int h[FRNG];
    const int bid = blockIdx.x;
    if (bid < HISTB) {
        const int type = bid & 1;
        const int gp = (bid >> 1) & 7;
        const int c = bid >> 4;
        const int lo = gp * FRNG;
        for (int i = threadIdx.x; i < FRNG; i += 1024) h[i] = 0;
        __syncthreads();
        const int4* a4 = reinterpret_cast<const int4*>((type ? dst : src) + c * CHUNK);
        for (int k = threadIdx.x; k < CHUNK / 4; k += 1024) {
            int4 v = a4[k];
            int i0 = v.x - lo, i1 = v.y - lo, i2 = v.z - lo, i3 = v.w - lo;
            if ((unsigned)i0 < FRNG) atomicAdd(&h[i0], 1);
            if ((unsigned)i1 < FRNG) atomicAdd(&h[i1], 1);
            if ((unsigned)i2 < FRNG) atomicAdd(&h[i2], 1);
            if ((unsigned)i3 < FRNG) atomicAdd(&h[i3], 1);
        }
        __syncthreads();
        // packed flush: word w of this range = counters for nodes (2w, 2w+1)
        unsigned int* o = (type ? hip : hop) + (size_t)c * (NN / 2) + gp * (FRNG / 2);
        for (int i = threadIdx.x; i < FRNG / 2; i += 1024)
            o[i] = (unsigned int)h[2 * i] | ((unsigned int)h[2 * i + 1] << 16);
    } else {
        // ---- W1 -> fragment-linear bf16 + (b1,W2) table (independent of hist) ----
        int idx = (bid - HISTB) * 1024 + threadIdx.x;
        if (idx < 4096) {
            int l = idx & 63, ks = (idx >> 6) & 3, nt = idx >> 8;
            int kbase = ks * 32 + ((l >> 4) << 3);
            int col = nt * 16 + (l & 15);
            bf16x8 r;
            #pragma unroll
            for (int i = 0; i < 8; ++i)
                r[i] = (short)f2bf(W1[(size_t)(kbase + i) * HID + col]);
            *reinterpret_cast<bf16x8*>(fragW + (size_t)idx * 8) = r;
        } else if (idx < 4096 + HID) {
            int n = idx - 4096;
            bw[n] = make_float2(b1[n], W2[n]);
        }
    }
}

// ---- norms + deg_in + per-block scan sums (scan1 merged) ----
__global__ void k_norms2(const unsigned int* __restrict__ hop, const unsigned int* __restrict__ hip,
                         float* __restrict__ nrm_out, float* __restrict__ nrm_in,
                         int* __restrict__ deg_in, int* __restrict__ partial) {
    __shared__ int sh[SCAN_BLK];
    int v = blockIdx.x * SCAN_BLK + threadIdx.x;
    int so = 0, si = 0;
    if (v < NN) {
        int w = v >> 1, sft = (v & 1) << 4;
        #pragma unroll
        for (int c = 0; c < NC; ++c) {
            so += (hop[(size_t)c * (NN / 2) + w] >> sft) & 0xFFFFu;
            si += (hip[(size_t)c * (NN / 2) + w] >> sft) & 0xFFFFu;
        }
        nrm_out[v] = rsqrtf(fmaxf((float)so, 1.0f));
        nrm_in[v]  = rsqrtf(fmaxf((float)si, 1.0f));
        deg_in[v]  = si;
    }
    sh[threadIdx.x] = si;
    __syncthreads();
    for (int off = SCAN_BLK / 2; off > 0; off >>= 1) {
        if (threadIdx.x < off) sh[threadIdx.x] += sh[threadIdx.x + off];
        __syncthreads();
    }
    if (threadIdx.x == 0) partial[blockIdx.x] = sh[0];
}

// ---- scan phase 2: wave-parallel exclusive scan of 391 partials ----
__global__ void k_scan2(int* __restrict__ partial) {
    int lane = threadIdx.x;
    int carry = 0;
    for (int c = 0; c < NSCAN; c += 64) {
        int idx = c + lane;
        int v = (idx < NSCAN) ? partial[idx] : 0;
        int s = v;
        #pragma unroll
        for (int off = 1; off < 64; off <<= 1) {
            int t = __shfl_up(s, off, 64);
            if (lane >= off) s += t;
        }
        if (idx < NSCAN) partial[idx] = s - v + carry;
        carry += __shfl(s, 63, 64);
    }
}

// ---- scan phase 3 + cbase (merged) ----
__global__ void k_scan3c(const int* __restrict__ deg_in, const int* __restrict__ partial,
                         int* __restrict__ offsets, const unsigned int* __restrict__ hip,
                         int* __restrict__ cbase) {
    __shared__ int sh[SCAN_BLK];
    int i = blockIdx.x * SCAN_BLK + threadIdx.x;
    int v = (i < NN) ? deg_in[i] : 0;
    sh[threadIdx.x] = v;
    __syncthreads();
    for (int off = 1; off < SCAN_BLK; off <<= 1) {
        int t = (threadIdx.x >= off) ? sh[threadIdx.x - off] : 0;
        __syncthreads();
        sh[threadIdx.x] += t;
        __syncthreads();
    }
    int ex = sh[threadIdx.x] - v + partial[blockIdx.x];
    if (i < NN) {
        offsets[i] = ex;
        int run = ex;
        int w = i >> 1, sft = (i & 1) << 4;
        #pragma unroll
        for (int c = 0; c < NC; ++c) {
            cbase[(size_t)c * NN + i] = run;
            run += (hip[(size_t)c * (NN / 2) + w] >> sft) & 0xFFFFu;
        }
    }
    if (i == 0) offsets[NN] = NE;
}

// ---- fused mid: CSR fill (0..255) ∥ scaled xconv (256..511) ----
__launch_bounds__(1024)
__global__ void k_mid(const int* __restrict__ src, const int* __restrict__ dst,
                      const int* __restrict__ cbase, int* __restrict__ csr_src,
                      const float* __restrict__ x, const float* __restrict__ nrm_out,
                      unsigned int* __restrict__ xs) {
    __shared__ int cur[FRNG];
    const int bid = blockIdx.x;
    if (bid < MIDF) {
        const int g = bid & (FGRP - 1);
        const int c = bid >> 3;
        const int lo = g * FRNG;
        const int* cb = cbase + (size_t)c * NN + lo;
        for (int i = threadIdx.x; i < FRNG; i += 1024) cur[i] = cb[i];
        __syncthreads();
        const int e0 = c * CHUNK;
        const int4* d4 = reinterpret_cast<const int4*>(dst + e0);
        for (int k = threadIdx.x; k < CHUNK / 4; k += 1024) {
            int4 v = d4[k];
            int e = e0 + k * 4;
            int i0 = v.x - lo, i1 = v.y - lo, i2 = v.z - lo, i3 = v.w - lo;
            if ((unsigned)i0 < FRNG) { int p = atomicAdd(&cur[i0], 1); csr_src[p] = src[e]; }
            if ((unsigned)i1 < FRNG) { int p = atomicAdd(&cur[i1], 1); csr_src[p] = src[e + 1]; }
            if ((unsigned)i2 < FRNG) { int p = atomicAdd(&cur[i2], 1); csr_src[p] = src[e + 2]; }
            if ((unsigned)i3 < FRNG) { int p = atomicAdd(&cur[i3], 1); csr_src[p] = src[e + 3]; }
        }
    } else {
        // xs = bf16(x * nrm_out[row]) — scaled at source
        const int nU2 = NN * (INF / 4);
        for (int i = (bid - MIDF) * 1024 + threadIdx.x; i < nU2; i += MIDX * 1024) {
            int row = i >> 5;
            float n = nrm_out[row];
            float4 v = *reinterpret_cast<const float4*>(x + (size_t)i * 4);
            uint2 r;
            r.x = f2bf(v.x * n) | (f2bf(v.y * n) << 16);
            r.y = f2bf(v.z * n) | (f2bf(v.w * n) << 16);
            *reinterpret_cast<uint2*>(xs + (size_t)i * 2) = r;
        }
    }
}

// ---- gather, 4-deep MLP + cache-pollution hints ----
// csr_src (once-read stream) via nontemporal loads, aggb (once-written
// stream) via nontemporal stores -> per-XCD L2 stays dedicated to xs.
__global__ void k_gather(const unsigned int* __restrict__ xs, const int* __restrict__ offsets,
                         const int* __restrict__ csr_src, const float* __restrict__ nrm_in,
                         unsigned int* __restrict__ aggb) {
    int row = blockIdx.x * 4 + (threadIdx.x >> 6);
    if (row >= NN) return;
    int lane = threadIdx.x & 63;
    int beg = offsets[row], end = offsets[row + 1];
    float a0 = 0.f, a1 = 0.f, b0 = 0.f, b1 = 0.f;
    float c0 = 0.f, c1 = 0.f, d0 = 0.f, d1 = 0.f;
    int j = beg;
    if (j + 4 <= end) {
        int s0 = __builtin_nontemporal_load(csr_src + j);
        int s1 = __builtin_nontemporal_load(csr_src + j + 1);
        int s2 = __builtin_nontemporal_load(csr_src + j + 2);
        int s3 = __builtin_nontemporal_load(csr_src + j + 3);
        while (true) {
            unsigned int p0 = xs[(size_t)s0 * 64 + lane];
            unsigned int p1 = xs[(size_t)s1 * 64 + lane];
            unsigned int p2 = xs[(size_t)s2 * 64 + lane];
            unsigned int p3 = xs[(size_t)s3 * 64 + lane];
            j += 4;
            bool more = (j + 4 <= end);
            if (more) {
                s0 = __builtin_nontemporal_load(csr_src + j);
                s1 = __builtin_nontemporal_load(csr_src + j + 1);
                s2 = __builtin_nontemporal_load(csr_src + j + 2);
                s3 = __builtin_nontemporal_load(csr_src + j + 3);
            }
            a0 += __uint_as_float(p0 << 16); a1 += __uint_as_float(p0 & 0xFFFF0000u);
            b0 += __uint_as_float(p1 << 16); b1 += __uint_as_float(p1 & 0xFFFF0000u);
            c0 += __uint_as_float(p2 << 16); c1 += __uint_as_float(p2 & 0xFFFF0000u);
            d0 += __uint_as_float(p3 << 16); d1 += __uint_as_float(p3 & 0xFFFF0000u);
            if (!more) break;
        }
    }
    for (; j < end; ++j) {
        unsigned int p0 = xs[(size_t)csr_src[j] * 64 + lane];
        a0 += __uint_as_float(p0 << 16);
        a1 += __uint_as_float(p0 & 0xFFFF0000u);
    }
    float ni = nrm_in[row];
    float lo = ((a0 + b0) + (c0 + d0)) * ni;
    float hi = ((a1 + b1) + (c1 + d1)) * ni;
    __builtin_nontemporal_store(f2bf(lo) | (f2bf(hi) << 16), aggb + (size_t)row * 64 + lane);
}

// ---- MFMA GEMM (no LDS) + relu + W2-dot + shfl-reduce -> z ----
__launch_bounds__(256)
__global__ void k_gemm(const unsigned short* __restrict__ aggb,
                       const unsigned short* __restrict__ fragW,
                       const float2* __restrict__ bw, const float* __restrict__ nrm_out,
                       float* __restrict__ z) {
    const int l = threadIdx.x & 63;
    const int w = threadIdx.x >> 6;
    const int r0 = blockIdx.x * 64 + w * 16;
    const int n15 = l & 15;
    const int hi = l >> 4;
    const int arow = r0 + n15;

    bf16x8 a[4];
    if (arow < NN) {
        #pragma unroll
        for (int ks = 0; ks < 4; ++ks)
            a[ks] = *reinterpret_cast<const bf16x8*>(aggb + (size_t)arow * INF + ks * 32 + (hi << 3));
    } else {
        #pragma unroll
        for (int ks = 0; ks < 4; ++ks) a[ks] = (bf16x8){0, 0, 0, 0, 0, 0, 0, 0};
    }

    float pacc[4] = {0.f, 0.f, 0.f, 0.f};
    #pragma unroll
    for (int nt = 0; nt < 16; ++nt) {
        f32x4 acc = {0.f, 0.f, 0.f, 0.f};
        #pragma unroll
        for (int ks = 0; ks < 4; ++ks) {
            bf16x8 b = *reinterpret_cast<const bf16x8*>(fragW + (size_t)(((nt * 4 + ks) * 64 + l) << 3));
            acc = __builtin_amdgcn_mfma_f32_16x16x32_bf16(a[ks], b, acc, 0, 0, 0);
        }
        float2 c = bw[nt * 16 + n15];
        #pragma unroll
        for (int g = 0; g < 4; ++g)
            pacc[g] += fmaxf(acc[g] + c.x, 0.f) * c.y;
    }
    #pragma unroll
    for (int off = 1; off < 16; off <<= 1) {
        #pragma unroll
        for (int g = 0; g < 4; ++g) pacc[g] += __shfl_xor(pacc[g], off, 64);
    }
    if (n15 == 0) {
        #pragma unroll
        for (int g = 0; g < 4; ++g) {
            int gr = r0 + (hi << 2) + g;
            if (gr < NN) z[gr] = nrm_out[gr] * pacc[g];
        }
    }
}

// ---- layer-2 gather + sigmoid: 16 lanes per node, shfl reduce ----
__global__ void k_out(const float* __restrict__ z, const int* __restrict__ offsets,
                      const int* __restrict__ csr_src, const float* __restrict__ nrm_in,
                      const float* __restrict__ b2, float* __restrict__ out) {
    int v = blockIdx.x * 16 + (threadIdx.x >> 4);
    if (v >= NN) return;
    int li = threadIdx.x & 15;
    int beg = offsets[v], end = offsets[v + 1];
    float s = 0.f;
    for (int j = beg + li; j < end; j += 16) s += z[csr_src[j]];
    #pragma unroll
    for (int off = 1; off < 16; off <<= 1) s += __shfl_xor(s, off, 64);
    if (li == 0) {
        float val = s * nrm_in[v] + b2[0];
        out[v] = 1.0f / (1.0f + expf(-val));
    }
}

extern "C" void kernel_launch(void* const* d_in, const int* in_sizes, int n_in,
                              void* d_out, int out_size, void* d_ws, size_t ws_size,
                              hipStream_t stream) {
    const float* x   = (const float*)d_in[0];
    const int*   src = (const int*)d_in[1];
    const int*   dst = (const int*)d_in[2];
    const float* W1  = (const float*)d_in[3];
    const float* b1  = (const float*)d_in[4];
    const float* W2  = (const float*)d_in[5];
    const float* b2  = (const float*)d_in[6];
    float* out = (float*)d_out;

    // workspace (r11-proven layout):
    //   hop/hip alias xs   (dead after scan3c; k_mid writes xs after)
    //   cbase aliases aggb (dead after k_mid; k_gather writes aggb after)
    int*   deg_in  = (int*)d_ws;                     // NN
    int*   offsets = deg_in + NN;                    // NN+1
    int*   partial = offsets + NN + 1;               // NSCAN
    int*   csr_src = partial + NSCAN;                // NE
    float* nrm_out = (float*)(csr_src + NE);         // NN
    float* nrm_in  = nrm_out + NN;                   // NN
    float* z       = nrm_in + NN;                    // NN
    float2* bw     = (float2*)(z + NN);              // HID
    unsigned int* xs   = (unsigned int*)(bw + HID);  // NN*64  (25.6 MB)
    unsigned int* aggb = xs + (size_t)NN * 64;       // NN*64  (25.6 MB)
    unsigned short* fragW = (unsigned short*)(aggb + (size_t)NN * 64);  // 64 KB
    unsigned int* hop = xs;                          // NC*NN/2 words (6.4 MB)
    unsigned int* hip = hop + (size_t)NC * (NN / 2); // NC*NN/2 words (6.4 MB)
    int* cbase = (int*)aggb;                         // NC*NN (12.8 MB)

    k_hist<<<HISTB + 5, 1024, 0, stream>>>(src, dst, hop, hip, W1, b1, W2, fragW, bw);
    k_norms2<<<NSCAN, SCAN_BLK, 0, stream>>>(hop, hip, nrm_out, nrm_in, deg_in, partial);
    k_scan2<<<1, 64, 0, stream>>>(partial);
    k_scan3c<<<NSCAN, SCAN_BLK, 0, stream>>>(deg_in, partial, offsets, hip, cbase);
    k_mid<<<MIDF + MIDX, 1024, 0, stream>>>(src, dst, cbase, csr_src, x, nrm_out, xs);
    k_gather<<<NN / 4, 256, 0, stream>>>(xs, offsets, csr_src, nrm_in, aggb);
    k_gemm<<<(NN + 63) / 64, 256, 0, stream>>>((const unsigned short*)aggb, fragW, bw, nrm_out, z);
    k_out<<<(NN + 15) / 16, 256, 0, stream>>>(z, offsets, csr_src, nrm_in, b2, out);
}

// Round 18
// 192.484 us; speedup vs baseline: 1.0277x; 1.0277x over previous
//
#include <hip/hip_runtime.h>
#include <math.h>

#define NN 100000
#define NE 1600000
#define INF 128
#define HID 256
#define SCAN_BLK 256
#define NSCAN ((NN + SCAN_BLK - 1) / SCAN_BLK)   // 391
#define FGRP 8                    // node-space partitions (fill)
#define FRNG (NN / FGRP)          // 12500 nodes per fill range
#define NC 32                     // edge-stream chunks
#define CHUNK (NE / NC)           // 50000 edges per chunk (< 65536 -> ushort-safe)
#define HRNG 25000                // nodes per hist block (2 ranges, packed ushort)
#define MIDF (FGRP * NC)          // 256 fill blocks
#define MIDX 256                  // xconv blocks
#define MIDW 5                    // wfrag blocks

typedef short bf16x8 __attribute__((ext_vector_type(8)));
typedef float f32x4 __attribute__((ext_vector_type(4)));

__device__ __forceinline__ unsigned int f2bf(float f) {
    unsigned int u = __float_as_uint(f);
    u = u + 0x7FFFu + ((u >> 16) & 1u);   // RNE
    return u >> 16;
}

// ---- degree histograms: packed 16-bit LDS counters, 2 ranges/block ----
__launch_bounds__(1024)
__global__ void k_hist(const int* __restrict__ src, const int* __restrict__ dst,
                       unsigned int* __restrict__ hop, unsigned int* __restrict__ hip) {
    __shared__ unsigned int h[HRNG / 2];
    const int type = blockIdx.x & 1;
    const int gp = (blockIdx.x >> 1) & 3;
    const int c = blockIdx.x >> 3;
    const int lo = gp * HRNG;
    for (int i = threadIdx.x; i < HRNG / 2; i += 1024) h[i] = 0;
    __syncthreads();
    const int4* a4 = reinterpret_cast<const int4*>((type ? dst : src) + c * CHUNK);
    for (int k = threadIdx.x; k < CHUNK / 4; k += 1024) {
        int4 v = a4[k];
        int i0 = v.x - lo, i1 = v.y - lo, i2 = v.z - lo, i3 = v.w - lo;
        if ((unsigned)i0 < HRNG) atomicAdd(&h[i0 >> 1], 1u << ((i0 & 1) << 4));
        if ((unsigned)i1 < HRNG) atomicAdd(&h[i1 >> 1], 1u << ((i1 & 1) << 4));
        if ((unsigned)i2 < HRNG) atomicAdd(&h[i2 >> 1], 1u << ((i2 & 1) << 4));
        if ((unsigned)i3 < HRNG) atomicAdd(&h[i3 >> 1], 1u << ((i3 & 1) << 4));
    }
    __syncthreads();
    unsigned int* o = (type ? hip : hop) + (size_t)c * (NN / 2) + gp * (HRNG / 2);
    for (int i = threadIdx.x; i < HRNG / 2; i += 1024) o[i] = h[i];
}

// ---- norms + deg_in + per-block scan sums (scan1 merged) ----
__global__ void k_norms2(const unsigned int* __restrict__ hop, const unsigned int* __restrict__ hip,
                         float* __restrict__ nrm_out, float* __restrict__ nrm_in,
                         int* __restrict__ deg_in, int* __restrict__ partial) {
    __shared__ int sh[SCAN_BLK];
    int v = blockIdx.x * SCAN_BLK + threadIdx.x;
    int so = 0, si = 0;
    if (v < NN) {
        int w = v >> 1, sft = (v & 1) << 4;
        #pragma unroll
        for (int c = 0; c < NC; ++c) {
            so += (hop[(size_t)c * (NN / 2) + w] >> sft) & 0xFFFFu;
            si += (hip[(size_t)c * (NN / 2) + w] >> sft) & 0xFFFFu;
        }
        nrm_out[v] = rsqrtf(fmaxf((float)so, 1.0f));
        nrm_in[v]  = rsqrtf(fmaxf((float)si, 1.0f));
        deg_in[v]  = si;
    }
    sh[threadIdx.x] = si;
    __syncthreads();
    for (int off = SCAN_BLK / 2; off > 0; off >>= 1) {
        if (threadIdx.x < off) sh[threadIdx.x] += sh[threadIdx.x + off];
        __syncthreads();
    }
    if (threadIdx.x == 0) partial[blockIdx.x] = sh[0];
}

// ---- scan phase 2: wave-parallel exclusive scan of 391 partials ----
__global__ void k_scan2(int* __restrict__ partial) {
    int lane = threadIdx.x;
    int carry = 0;
    for (int c = 0; c < NSCAN; c += 64) {
        int idx = c + lane;
        int v = (idx < NSCAN) ? partial[idx] : 0;
        int s = v;
        #pragma unroll
        for (int off = 1; off < 64; off <<= 1) {
            int t = __shfl_up(s, off, 64);
            if (lane >= off) s += t;
        }
        if (idx < NSCAN) partial[idx] = s - v + carry;
        carry += __shfl(s, 63, 64);
    }
}

// ---- scan phase 3 + cbase (merged) ----
__global__ void k_scan3c(const int* __restrict__ deg_in, const int* __restrict__ partial,
                         int* __restrict__ offsets, const unsigned int* __restrict__ hip,
                         int* __restrict__ cbase) {
    __shared__ int sh[SCAN_BLK];
    int i = blockIdx.x * SCAN_BLK + threadIdx.x;
    int v = (i < NN) ? deg_in[i] : 0;
    sh[threadIdx.x] = v;
    __syncthreads();
    for (int off = 1; off < SCAN_BLK; off <<= 1) {
        int t = (threadIdx.x >= off) ? sh[threadIdx.x - off] : 0;
        __syncthreads();
        sh[threadIdx.x] += t;
        __syncthreads();
    }
    int ex = sh[threadIdx.x] - v + partial[blockIdx.x];
    if (i < NN) {
        offsets[i] = ex;
        int run = ex;
        int w = i >> 1, sft = (i & 1) << 4;
        #pragma unroll
        for (int c = 0; c < NC; ++c) {
            cbase[(size_t)c * NN + i] = run;
            run += (hip[(size_t)c * (NN / 2) + w] >> sft) & 0xFFFFu;
        }
    }
    if (i == 0) offsets[NN] = NE;
}

// ---- fused mid: CSR fill (0..255) ∥ scaled xconv (256..511) ∥ wfrag (512..516) ----
__launch_bounds__(1024)
__global__ void k_mid(const int* __restrict__ src, const int* __restrict__ dst,
                      const int* __restrict__ cbase, int* __restrict__ csr_src,
                      const float* __restrict__ x, const float* __restrict__ nrm_out,
                      unsigned int* __restrict__ xs,
                      const float* __restrict__ W1, const float* __restrict__ b1,
                      const float* __restrict__ W2, unsigned short* __restrict__ fragW,
                      float2* __restrict__ bw) {
    __shared__ int cur[FRNG];
    const int bid = blockIdx.x;
    if (bid < MIDF) {
        const int g = bid & (FGRP - 1);
        const int c = bid >> 3;
        const int lo = g * FRNG;
        const int* cb = cbase + (size_t)c * NN + lo;
        for (int i = threadIdx.x; i < FRNG; i += 1024) cur[i] = cb[i];
        __syncthreads();
        const int e0 = c * CHUNK;
        const int4* d4 = reinterpret_cast<const int4*>(dst + e0);
        for (int k = threadIdx.x; k < CHUNK / 4; k += 1024) {
            int4 v = d4[k];
            int e = e0 + k * 4;
            int i0 = v.x - lo, i1 = v.y - lo, i2 = v.z - lo, i3 = v.w - lo;
            if ((unsigned)i0 < FRNG) { int p = atomicAdd(&cur[i0], 1); csr_src[p] = src[e]; }
            if ((unsigned)i1 < FRNG) { int p = atomicAdd(&cur[i1], 1); csr_src[p] = src[e + 1]; }
            if ((unsigned)i2 < FRNG) { int p = atomicAdd(&cur[i2], 1); csr_src[p] = src[e + 2]; }
            if ((unsigned)i3 < FRNG) { int p = atomicAdd(&cur[i3], 1); csr_src[p] = src[e + 3]; }
        }
    } else if (bid < MIDF + MIDX) {
        // xs = bf16(x * nrm_out[row]) — scaled at source, gather stays pure
        const int nU2 = NN * (INF / 4);
        for (int i = (bid - MIDF) * 1024 + threadIdx.x; i < nU2; i += MIDX * 1024) {
            int row = i >> 5;
            float n = nrm_out[row];
            float4 v = *reinterpret_cast<const float4*>(x + (size_t)i * 4);
            uint2 r;
            r.x = f2bf(v.x * n) | (f2bf(v.y * n) << 16);
            r.y = f2bf(v.z * n) | (f2bf(v.w * n) << 16);
            *reinterpret_cast<uint2*>(xs + (size_t)i * 2) = r;
        }
    } else {
        int idx = (bid - MIDF - MIDX) * 1024 + threadIdx.x;
        if (idx < 4096) {
            int l = idx & 63, ks = (idx >> 6) & 3, nt = idx >> 8;
            int kbase = ks * 32 + ((l >> 4) << 3);
            int col = nt * 16 + (l & 15);
            bf16x8 r;
            #pragma unroll
            for (int i = 0; i < 8; ++i)
                r[i] = (short)f2bf(W1[(size_t)(kbase + i) * HID + col]);
            *reinterpret_cast<bf16x8*>(fragW + (size_t)idx * 8) = r;
        } else if (idx < 4096 + HID) {
            int n = idx - 4096;
            bw[n] = make_float2(b1[n], W2[n]);
        }
    }
}

// ---- gather, 4-deep MLP (measured optimum): aggb[v] = bf16(nrm_in[v]*sum xs[src]) ----
__global__ void k_gather(const unsigned int* __restrict__ xs, const int* __restrict__ offsets,
                         const int* __restrict__ csr_src, const float* __restrict__ nrm_in,
                         unsigned int* __restrict__ aggb) {
    int row = blockIdx.x * 4 + (threadIdx.x >> 6);
    if (row >= NN) return;
    int lane = threadIdx.x & 63;
    int beg = offsets[row], end = offsets[row + 1];
    float a0 = 0.f, a1 = 0.f, b0 = 0.f, b1 = 0.f;
    float c0 = 0.f, c1 = 0.f, d0 = 0.f, d1 = 0.f;
    int j = beg;
    if (j + 4 <= end) {
        int s0 = csr_src[j], s1 = csr_src[j + 1], s2 = csr_src[j + 2], s3 = csr_src[j + 3];
        while (true) {
            unsigned int p0 = xs[(size_t)s0 * 64 + lane];
            unsigned int p1 = xs[(size_t)s1 * 64 + lane];
            unsigned int p2 = xs[(size_t)s2 * 64 + lane];
            unsigned int p3 = xs[(size_t)s3 * 64 + lane];
            j += 4;
            bool more = (j + 4 <= end);
            if (more) {
                s0 = csr_src[j]; s1 = csr_src[j + 1]; s2 = csr_src[j + 2]; s3 = csr_src[j + 3];
            }
            a0 += __uint_as_float(p0 << 16); a1 += __uint_as_float(p0 & 0xFFFF0000u);
            b0 += __uint_as_float(p1 << 16); b1 += __uint_as_float(p1 & 0xFFFF0000u);
            c0 += __uint_as_float(p2 << 16); c1 += __uint_as_float(p2 & 0xFFFF0000u);
            d0 += __uint_as_float(p3 << 16); d1 += __uint_as_float(p3 & 0xFFFF0000u);
            if (!more) break;
        }
    }
    for (; j < end; ++j) {
        unsigned int p0 = xs[(size_t)csr_src[j] * 64 + lane];
        a0 += __uint_as_float(p0 << 16);
        a1 += __uint_as_float(p0 & 0xFFFF0000u);
    }
    float ni = nrm_in[row];
    float lo = ((a0 + b0) + (c0 + d0)) * ni;
    float hi = ((a1 + b1) + (c1 + d1)) * ni;
    aggb[(size_t)row * 64 + lane] = f2bf(lo) | (f2bf(hi) << 16);
}

// ---- MFMA GEMM (no LDS) + relu + W2-dot + shfl-reduce -> z ----
__launch_bounds__(256)
__global__ void k_gemm(const unsigned short* __restrict__ aggb,
                       const unsigned short* __restrict__ fragW,
                       const float2* __restrict__ bw, const float* __restrict__ nrm_out,
                       float* __restrict__ z) {
    const int l = threadIdx.x & 63;
    const int w = threadIdx.x >> 6;
    const int r0 = blockIdx.x * 64 + w * 16;
    const int n15 = l & 15;
    const int hi = l >> 4;
    const int arow = r0 + n15;

    bf16x8 a[4];
    if (arow < NN) {
        #pragma unroll
        for (int ks = 0; ks < 4; ++ks)
            a[ks] = *reinterpret_cast<const bf16x8*>(aggb + (size_t)arow * INF + ks * 32 + (hi << 3));
    } else {
        #pragma unroll
        for (int ks = 0; ks < 4; ++ks) a[ks] = (bf16x8){0, 0, 0, 0, 0, 0, 0, 0};
    }

    float pacc[4] = {0.f, 0.f, 0.f, 0.f};
    #pragma unroll
    for (int nt = 0; nt < 16; ++nt) {
        f32x4 acc = {0.f, 0.f, 0.f, 0.f};
        #pragma unroll
        for (int ks = 0; ks < 4; ++ks) {
            bf16x8 b = *reinterpret_cast<const bf16x8*>(fragW + (size_t)(((nt * 4 + ks) * 64 + l) << 3));
            acc = __builtin_amdgcn_mfma_f32_16x16x32_bf16(a[ks], b, acc, 0, 0, 0);
        }
        float2 c = bw[nt * 16 + n15];
        #pragma unroll
        for (int g = 0; g < 4; ++g)
            pacc[g] += fmaxf(acc[g] + c.x, 0.f) * c.y;
    }
    #pragma unroll
    for (int off = 1; off < 16; off <<= 1) {
        #pragma unroll
        for (int g = 0; g < 4; ++g) pacc[g] += __shfl_xor(pacc[g], off, 64);
    }
    if (n15 == 0) {
        #pragma unroll
        for (int g = 0; g < 4; ++g) {
            int gr = r0 + (hi << 2) + g;
            if (gr < NN) z[gr] = nrm_out[gr] * pacc[g];
        }
    }
}

// ---- layer-2 gather + sigmoid: 16 lanes per node, shfl reduce ----
__global__ void k_out(const float* __restrict__ z, const int* __restrict__ offsets,
                      const int* __restrict__ csr_src, const float* __restrict__ nrm_in,
                      const float* __restrict__ b2, float* __restrict__ out) {
    int v = blockIdx.x * 16 + (threadIdx.x >> 4);
    if (v >= NN) return;
    int li = threadIdx.x & 15;
    int beg = offsets[v], end = offsets[v + 1];
    float s = 0.f;
    for (int j = beg + li; j < end; j += 16) s += z[csr_src[j]];
    #pragma unroll
    for (int off = 1; off < 16; off <<= 1) s += __shfl_xor(s, off, 64);
    if (li == 0) {
        float val = s * nrm_in[v] + b2[0];
        out[v] = 1.0f / (1.0f + expf(-val));
    }
}

extern "C" void kernel_launch(void* const* d_in, const int* in_sizes, int n_in,
                              void* d_out, int out_size, void* d_ws, size_t ws_size,
                              hipStream_t stream) {
    const float* x   = (const float*)d_in[0];
    const int*   src = (const int*)d_in[1];
    const int*   dst = (const int*)d_in[2];
    const float* W1  = (const float*)d_in[3];
    const float* b1  = (const float*)d_in[4];
    const float* W2  = (const float*)d_in[5];
    const float* b2  = (const float*)d_in[6];
    float* out = (float*)d_out;

    // workspace (r11-proven layout):
    //   hop/hip alias xs   (dead after scan3c; k_mid writes xs after)
    //   cbase aliases aggb (dead after k_mid; k_gather writes aggb after)
    int*   deg_in  = (int*)d_ws;                     // NN
    int*   offsets = deg_in + NN;                    // NN+1
    int*   partial = offsets + NN + 1;               // NSCAN
    int*   csr_src = partial + NSCAN;                // NE
    float* nrm_out = (float*)(csr_src + NE);         // NN
    float* nrm_in  = nrm_out + NN;                   // NN
    float* z       = nrm_in + NN;                    // NN
    float2* bw     = (float2*)(z + NN);              // HID
    unsigned int* xs   = (unsigned int*)(bw + HID);  // NN*64  (25.6 MB)
    unsigned int* aggb = xs + (size_t)NN * 64;       // NN*64  (25.6 MB)
    unsigned short* fragW = (unsigned short*)(aggb + (size_t)NN * 64);  // 64 KB
    unsigned int* hop = xs;                          // NC*NN/2 words (6.4 MB)
    unsigned int* hip = hop + (size_t)NC * (NN / 2); // NC*NN/2 words (6.4 MB)
    int* cbase = (int*)aggb;                         // NC*NN (12.8 MB)

    k_hist<<<2 * 4 * NC, 1024, 0, stream>>>(src, dst, hop, hip);
    k_norms2<<<NSCAN, SCAN_BLK, 0, stream>>>(hop, hip, nrm_out, nrm_in, deg_in, partial);
    k_scan2<<<1, 64, 0, stream>>>(partial);
    k_scan3c<<<NSCAN, SCAN_BLK, 0, stream>>>(deg_in, partial, offsets, hip, cbase);
    k_mid<<<MIDF + MIDX + MIDW, 1024, 0, stream>>>(src, dst, cbase, csr_src,
                                                   x, nrm_out, xs, W1, b1, W2, fragW, bw);
    k_gather<<<NN / 4, 256, 0, stream>>>(xs, offsets, csr_src, nrm_in, aggb);
    k_gemm<<<(NN + 63) / 64, 256, 0, stream>>>((const unsigned short*)aggb, fragW, bw, nrm_out, z);
    k_out<<<(NN + 15) / 16, 256, 0, stream>>>(z, offsets, csr_src, nrm_in, b2, out);
}